// Round 6
// baseline (323.747 us; speedup 1.0000x reference)
//
#include <hip/hip_runtime.h>

#define B_ 4
#define N_ 16384
#define C_ 128
#define M_ 1024
#define K_ 32
#define NTOT (B_*M_*K_)   /* 131072 */
#define RAD2 0.16f
#define EPS_ 1e-5f

typedef unsigned short ushort_t;
typedef __bf16 bf16x8 __attribute__((ext_vector_type(8)));
typedef float f32x4 __attribute__((ext_vector_type(4)));

__device__ __forceinline__ float b2f(ushort_t u){
  unsigned int x = ((unsigned int)u) << 16;
  return __builtin_bit_cast(float, x);
}
__device__ __forceinline__ ushort_t f2b(float f){
  unsigned int u = __builtin_bit_cast(unsigned int, f);
  unsigned int r = (u + 0x7FFFu + ((u >> 16) & 1u)) >> 16;
  return (ushort_t)r;
}

// ---------------- ball query: 1 wave per query, no LDS, no barriers ---------
__global__ __launch_bounds__(256) void ball_query_k(
    const float* __restrict__ xyz, const int* __restrict__ indices,
    float* __restrict__ new_xyz, int* __restrict__ idx)
{
  int t = threadIdx.x;
  int wv = t >> 6, lane = t & 63;
  int g = blockIdx.x*4 + wv;
  int b = g >> 10;
  const float* pb = xyz + (size_t)b*N_*3;
  const float4* pb4 = (const float4*)pb;
  int qi = indices[g];
  float qx = pb[qi*3+0], qy = pb[qi*3+1], qz = pb[qi*3+2];
  if (lane < 3) new_xyz[g*3 + lane] = pb[qi*3 + lane];

  int cnt = 0, firstIdx = 0;
  int* op = idx + g*K_;

  float4 buf0[6], buf1[6];
  #pragma unroll
  for (int i = 0; i < 6; i++) buf0[i] = pb4[lane*6 + i];

  auto process = [&](const float4* buf, int chunk){
    const float* f = (const float*)buf;
    unsigned int local_mask = 0;
    #pragma unroll
    for (int j = 0; j < 8; j++){
      float dx = f[j*3+0]-qx, dy = f[j*3+1]-qy, dz = f[j*3+2]-qz;
      if (dx*dx + dy*dy + dz*dz < RAD2) local_mask |= (1u << j);
    }
    if (__ballot(local_mask != 0) == 0ull) return;
    int base = chunk*512;
    int lcnt = __popc(local_mask);
    int incl = lcnt;
    #pragma unroll
    for (int d = 1; d < 64; d <<= 1){
      int tt = __shfl_up(incl, d);
      if (lane >= d) incl += tt;
    }
    int excl = incl - lcnt;
    int total = __shfl(incl, 63);
    if (cnt == 0){
      int lf = local_mask ? (lane*8 + __builtin_ctz(local_mask)) : 0x7fffffff;
      #pragma unroll
      for (int d = 1; d < 64; d <<= 1) lf = min(lf, __shfl_xor(lf, d));
      firstIdx = base + lf;
    }
    int sl = cnt + excl;
    unsigned int m = local_mask;
    while (m && sl < K_){
      int j = __builtin_ctz(m); m &= m - 1u;
      op[sl++] = base + lane*8 + j;
    }
    cnt += total;
  };

  for (int chunk = 0; chunk < 32; chunk += 2){
    if (chunk + 1 < 32){
      #pragma unroll
      for (int i = 0; i < 6; i++) buf1[i] = pb4[(chunk+1)*384 + lane*6 + i];
    }
    process(buf0, chunk);
    if (cnt >= K_) break;
    if (chunk + 2 < 32){
      #pragma unroll
      for (int i = 0; i < 6; i++) buf0[i] = pb4[(chunk+2)*384 + lane*6 + i];
    }
    process(buf1, chunk + 1);
    if (cnt >= K_) break;
  }
  if (cnt < K_){
    for (int s = cnt + lane; s < K_; s += 64) op[s] = firstIdx;
  }
}

// ---------------- features (B,C,N) f32 -> (B,N,C) bf16 ----------------------
__global__ __launch_bounds__(256) void transpose_feat_k(
    const float* __restrict__ feat, ushort_t* __restrict__ ftr_t)
{
  __shared__ float T[32][133];
  int bi = blockIdx.x;
  int b = bi >> 9, ntile = bi & 511;
  int n0 = ntile * 32;
  int t = threadIdx.x;
  int nl = t & 31;
  #pragma unroll
  for (int ci = 0; ci < 16; ci++){
    int c = ci*8 + (t >> 5);
    T[nl][c] = feat[((size_t)b*C_ + c)*N_ + n0 + nl];
  }
  __syncthreads();
  #pragma unroll
  for (int ii = 0; ii < 2; ii++){
    int v = ii*256 + t;
    int n2 = v >> 4, seg = v & 15;
    union { ushort_t u[8]; uint4 q; } pk;
    #pragma unroll
    for (int j = 0; j < 8; j++) pk.u[j] = f2b(T[n2][seg*8 + j]);
    *(uint4*)(ftr_t + ((size_t)b*N_ + n0 + n2)*C_ + seg*8) = pk.q;
  }
}

// ---------------- weights f32 -> bf16 (W1 reordered: feat|xyz|0, stride 160) -
__global__ __launch_bounds__(256) void prep_w_k(
    const float* __restrict__ w1, const float* __restrict__ w2, const float* __restrict__ w3,
    ushort_t* __restrict__ W1b, ushort_t* __restrict__ W2b, ushort_t* __restrict__ W3b)
{
  const int T1 = 128*160, T2 = 128*128, T3 = 256*128;
  for (int e = blockIdx.x*256 + threadIdx.x; e < T1+T2+T3; e += gridDim.x*256){
    if (e < T1){
      int o = e / 160, c = e % 160;
      float v = 0.f;
      if (c < 128) v = w1[o*131 + 3 + c];
      else if (c < 131) v = w1[o*131 + (c - 128)];
      W1b[e] = f2b(v);
    } else if (e < T1+T2){
      int e2 = e - T1;
      W2b[e2] = f2b(w2[e2]);
    } else {
      int e3 = e - T1 - T2;
      W3b[e3] = f2b(w3[e3]);
    }
  }
}

// ---------------- conv1: gather (feat|xyzdiff) -> GEMM, W in registers ------
// GPB=2, grid 2048: 8 blocks/CU demanded so occupancy is resource-capped,
// not grid-capped (round-5 counters: 2 blocks/CU -> 15% occupancy, idle).
__global__ __launch_bounds__(256, 3) void conv1_k(
    const float* __restrict__ xyz, const ushort_t* __restrict__ ftr_t,
    const int* __restrict__ idx, const float* __restrict__ new_xyz,
    const ushort_t* __restrict__ W1b, const float* __restrict__ b1,
    ushort_t* __restrict__ Y1, float* __restrict__ sumO, float* __restrict__ sqO)
{
  __shared__ alignas(16) ushort_t Xs[32*168];
  __shared__ alignas(16) float Ys[32*132];
  int t = threadIdx.x;
  int wv = t >> 6, lane = t & 63, quad = lane >> 4, l15 = lane & 15;
  int row = t >> 3, chunk = t & 7;

  if (t < 128){
    int rr = t >> 2, cc = t & 3;
    *(uint4*)(Xs + rr*168 + 128 + cc*8) = make_uint4(0,0,0,0);
  }
  bf16x8 wf[2][5];
  #pragma unroll
  for (int nt = 0; nt < 2; nt++)
    #pragma unroll
    for (int kt = 0; kt < 5; kt++)
      wf[nt][kt] = *(const bf16x8*)(W1b + (wv*32 + nt*16 + l15)*160 + kt*32 + quad*8);
  float bs_r[2] = { b1[wv*32 + l15], b1[wv*32 + 16 + l15] };
  float s[2] = {0.f,0.f}, s2[2] = {0.f,0.f};

  const int GPB = 2;
  int g0 = blockIdx.x * GPB;
  for (int i = 0; i < GPB; i++){
    int g = g0 + i;
    int b = g >> 10;
    int n = idx[g*K_ + row];
    const ushort_t* src = ftr_t + ((size_t)b*N_ + n)*C_ + chunk*16;
    uint4 q0 = *(const uint4*)src;
    uint4 q1 = *(const uint4*)(src + 8);
    *(uint4*)(Xs + row*168 + chunk*16) = q0;
    *(uint4*)(Xs + row*168 + chunk*16 + 8) = q1;
    if (t < 32){
      int n2 = idx[g*K_ + t];
      const float* pp = xyz + ((size_t)b*N_ + n2)*3;
      const float* qq = new_xyz + (size_t)g*3;
      unsigned int u0 = (unsigned int)f2b(pp[0]-qq[0]) | ((unsigned int)f2b(pp[1]-qq[1]) << 16);
      unsigned int u1 = (unsigned int)f2b(pp[2]-qq[2]);
      *(uint2*)(Xs + t*168 + 128) = make_uint2(u0, u1);
    }
    __syncthreads();
    bf16x8 af[2][5];
    #pragma unroll
    for (int mt = 0; mt < 2; mt++)
      #pragma unroll
      for (int kt = 0; kt < 5; kt++)
        af[mt][kt] = *(const bf16x8*)(Xs + (mt*16 + l15)*168 + kt*32 + quad*8);
    f32x4 acc[2][2];
    #pragma unroll
    for (int nt = 0; nt < 2; nt++){ acc[nt][0] = (f32x4){0,0,0,0}; acc[nt][1] = (f32x4){0,0,0,0}; }
    #pragma unroll
    for (int nt = 0; nt < 2; nt++)
      #pragma unroll
      for (int kt = 0; kt < 5; kt++){
        acc[nt][0] = __builtin_amdgcn_mfma_f32_16x16x32_bf16(af[0][kt], wf[nt][kt], acc[nt][0], 0,0,0);
        acc[nt][1] = __builtin_amdgcn_mfma_f32_16x16x32_bf16(af[1][kt], wf[nt][kt], acc[nt][1], 0,0,0);
      }
    #pragma unroll
    for (int nt = 0; nt < 2; nt++){
      int o = wv*32 + nt*16 + l15;
      #pragma unroll
      for (int mt = 0; mt < 2; mt++)
        #pragma unroll
        for (int r = 0; r < 4; r++){
          float v = acc[nt][mt][r] + bs_r[nt];
          s[nt] += v; s2[nt] += v*v;
          Ys[(mt*16 + quad*4 + r)*132 + o] = v;
        }
    }
    __syncthreads();
    {
      const float* yp = &Ys[row*132 + chunk*16];
      f32x4 y0 = *(const f32x4*)(yp);
      f32x4 y1 = *(const f32x4*)(yp + 4);
      f32x4 y2 = *(const f32x4*)(yp + 8);
      f32x4 y3 = *(const f32x4*)(yp + 12);
      union { ushort_t u[8]; uint4 q; } p0, p1;
      #pragma unroll
      for (int j = 0; j < 4; j++){
        p0.u[j] = f2b(y0[j]); p0.u[4+j] = f2b(y1[j]);
        p1.u[j] = f2b(y2[j]); p1.u[4+j] = f2b(y3[j]);
      }
      ushort_t* dst = Y1 + ((size_t)g*K_ + row)*128 + chunk*16;
      *(uint4*)dst = p0.q;
      *(uint4*)(dst + 8) = p1.q;
    }
  }
  #pragma unroll
  for (int nt = 0; nt < 2; nt++){
    s[nt]  += __shfl_xor(s[nt], 16);  s[nt]  += __shfl_xor(s[nt], 32);
    s2[nt] += __shfl_xor(s2[nt], 16); s2[nt] += __shfl_xor(s2[nt], 32);
    if (quad == 0){
      int o = wv*32 + nt*16 + l15;
      atomicAdd(&sumO[o], s[nt]);
      atomicAdd(&sqO[o], s2[nt]);
    }
  }
}

// ---------------- conv2/conv3: BN(prev)+relu staging, W in registers --------
template<int COUT, bool MAXMIN>
__global__ __launch_bounds__(256, 3) void convB_k(
    const ushort_t* __restrict__ Yin, const ushort_t* __restrict__ Wb,
    const float* __restrict__ bias, const float* __restrict__ g_bn,
    const float* __restrict__ beta_bn, const float* __restrict__ sumI,
    const float* __restrict__ sqI, ushort_t* __restrict__ Yout,
    unsigned int* __restrict__ Ymm, float* __restrict__ sumO, float* __restrict__ sqO)
{
  constexpr int NT = COUT/64;
  __shared__ alignas(16) ushort_t Xs[32*136];
  __shared__ alignas(16) float Ys[MAXMIN ? 4 : 32*132];
  int t = threadIdx.x;
  int wv = t >> 6, lane = t & 63, quad = lane >> 4, l15 = lane & 15;
  int row = t >> 3, chunk = t & 7;

  float a_r[16], d_r[16];
  #pragma unroll
  for (int j = 0; j < 16; j++){
    int c = chunk*16 + j;
    float mu  = sumI[c] * (1.f/NTOT);
    float var = sqI[c]  * (1.f/NTOT) - mu*mu;
    float a = g_bn[c] * rsqrtf(var + EPS_);
    a_r[j] = a; d_r[j] = beta_bn[c] - a*mu;
  }
  bf16x8 wf[NT][4];
  #pragma unroll
  for (int nt = 0; nt < NT; nt++)
    #pragma unroll
    for (int kt = 0; kt < 4; kt++)
      wf[nt][kt] = *(const bf16x8*)(Wb + (wv*(NT*16) + nt*16 + l15)*128 + kt*32 + quad*8);
  float bs_r[NT];
  #pragma unroll
  for (int nt = 0; nt < NT; nt++) bs_r[nt] = bias[wv*(NT*16) + nt*16 + l15];
  float s[NT], s2[NT];
  #pragma unroll
  for (int nt = 0; nt < NT; nt++){ s[nt] = 0.f; s2[nt] = 0.f; }

  const int GPB = 2;
  int g0 = blockIdx.x * GPB;
  uint4 r0, r1;
  {
    const ushort_t* src = Yin + ((size_t)g0*K_ + row)*128 + chunk*16;
    r0 = *(const uint4*)src; r1 = *(const uint4*)(src + 8);
  }
  for (int i = 0; i < GPB; i++){
    int g = g0 + i;
    union { ushort_t u[8]; uint4 q; } i0, i1, o0, o1;
    i0.q = r0; i1.q = r1;
    #pragma unroll
    for (int j = 0; j < 8; j++){
      o0.u[j] = f2b(fmaxf(a_r[j]  *b2f(i0.u[j]) + d_r[j],   0.f));
      o1.u[j] = f2b(fmaxf(a_r[8+j]*b2f(i1.u[j]) + d_r[8+j], 0.f));
    }
    *(uint4*)(Xs + row*136 + chunk*16) = o0.q;
    *(uint4*)(Xs + row*136 + chunk*16 + 8) = o1.q;
    if (i + 1 < GPB){
      const ushort_t* src = Yin + ((size_t)(g+1)*K_ + row)*128 + chunk*16;
      r0 = *(const uint4*)src; r1 = *(const uint4*)(src + 8);
    }
    __syncthreads();
    bf16x8 af[2][4];
    #pragma unroll
    for (int mt = 0; mt < 2; mt++)
      #pragma unroll
      for (int kt = 0; kt < 4; kt++)
        af[mt][kt] = *(const bf16x8*)(Xs + (mt*16 + l15)*136 + kt*32 + quad*8);
    f32x4 acc[NT][2];
    #pragma unroll
    for (int nt = 0; nt < NT; nt++){ acc[nt][0] = (f32x4){0,0,0,0}; acc[nt][1] = (f32x4){0,0,0,0}; }
    #pragma unroll
    for (int nt = 0; nt < NT; nt++)
      #pragma unroll
      for (int kt = 0; kt < 4; kt++){
        acc[nt][0] = __builtin_amdgcn_mfma_f32_16x16x32_bf16(af[0][kt], wf[nt][kt], acc[nt][0], 0,0,0);
        acc[nt][1] = __builtin_amdgcn_mfma_f32_16x16x32_bf16(af[1][kt], wf[nt][kt], acc[nt][1], 0,0,0);
      }
    if constexpr (!MAXMIN){
      #pragma unroll
      for (int nt = 0; nt < NT; nt++){
        int o = wv*(NT*16) + nt*16 + l15;
        #pragma unroll
        for (int mt = 0; mt < 2; mt++)
          #pragma unroll
          for (int r = 0; r < 4; r++){
            float v = acc[nt][mt][r] + bs_r[nt];
            s[nt] += v; s2[nt] += v*v;
            Ys[(mt*16 + quad*4 + r)*132 + o] = v;
          }
      }
      __syncthreads();
      const float* yp = &Ys[row*132 + chunk*16];
      f32x4 y0 = *(const f32x4*)(yp);
      f32x4 y1 = *(const f32x4*)(yp + 4);
      f32x4 y2 = *(const f32x4*)(yp + 8);
      f32x4 y3 = *(const f32x4*)(yp + 12);
      union { ushort_t u[8]; uint4 q; } p0, p1;
      #pragma unroll
      for (int j = 0; j < 4; j++){
        p0.u[j] = f2b(y0[j]); p0.u[4+j] = f2b(y1[j]);
        p1.u[j] = f2b(y2[j]); p1.u[4+j] = f2b(y3[j]);
      }
      ushort_t* dst = Yout + ((size_t)g*K_ + row)*128 + chunk*16;
      *(uint4*)dst = p0.q;
      *(uint4*)(dst + 8) = p1.q;
    } else {
      #pragma unroll
      for (int nt = 0; nt < NT; nt++){
        float v0 = acc[nt][0][0] + bs_r[nt];
        float mx = v0, mn = v0;
        s[nt] += v0; s2[nt] += v0*v0;
        #pragma unroll
        for (int mt = 0; mt < 2; mt++)
          #pragma unroll
          for (int r = 0; r < 4; r++){
            if (mt == 0 && r == 0) continue;
            float v = acc[nt][mt][r] + bs_r[nt];
            s[nt] += v; s2[nt] += v*v;
            mx = fmaxf(mx, v); mn = fminf(mn, v);
          }
        mx = fmaxf(mx, __shfl_xor(mx, 16)); mx = fmaxf(mx, __shfl_xor(mx, 32));
        mn = fminf(mn, __shfl_xor(mn, 16)); mn = fminf(mn, __shfl_xor(mn, 32));
        if (quad == 0){
          int o = wv*64 + nt*16 + l15;
          Ymm[(size_t)g*256 + o] = (unsigned int)f2b(mx) | ((unsigned int)f2b(mn) << 16);
        }
      }
      __syncthreads();
    }
  }
  #pragma unroll
  for (int nt = 0; nt < NT; nt++){
    s[nt]  += __shfl_xor(s[nt], 16);  s[nt]  += __shfl_xor(s[nt], 32);
    s2[nt] += __shfl_xor(s2[nt], 16); s2[nt] += __shfl_xor(s2[nt], 32);
    if (quad == 0){
      int o = wv*(NT*16) + nt*16 + l15;
      atomicAdd(&sumO[o], s[nt]);
      atomicAdd(&sqO[o], s2[nt]);
    }
  }
}

// ---------------- finalize: BN3 from max/min pairs, transposed store --------
__global__ __launch_bounds__(256) void finalize_k(
    const unsigned int* __restrict__ Ymm, const float* __restrict__ g3,
    const float* __restrict__ beta3, const float* __restrict__ sum3,
    const float* __restrict__ sq3, float* __restrict__ out)
{
  __shared__ float T[16][264];
  __shared__ float abn[256], dbn[256];
  int t = threadIdx.x;
  int b = blockIdx.x >> 6;
  int m0 = (blockIdx.x & 63) * 16;
  {
    float mu  = sum3[t] * (1.f/NTOT);
    float var = sq3[t]  * (1.f/NTOT) - mu*mu;
    float a = g3[t] * rsqrtf(var + EPS_);
    abn[t] = a; dbn[t] = beta3[t] - a*mu;
  }
  __syncthreads();
  #pragma unroll
  for (int i = 0; i < 4; i++){
    int v4 = i*256 + t;
    int m = v4 >> 6, oq = (v4 & 63) * 4;
    uint4 w = *(const uint4*)(Ymm + ((size_t)(b*M_ + m0 + m))*256 + oq);
    unsigned int wsv[4] = {w.x, w.y, w.z, w.w};
    float r[4];
    #pragma unroll
    for (int j = 0; j < 4; j++){
      int o = oq + j;
      float mx = b2f((ushort_t)(wsv[j] & 0xffffu));
      float mn = b2f((ushort_t)(wsv[j] >> 16));
      float a = abn[o];
      float val = (a >= 0.f) ? (a*mx + dbn[o]) : (a*mn + dbn[o]);
      r[j] = fmaxf(val, 0.f);
    }
    *(f32x4*)(&T[m][oq]) = *(f32x4*)r;
  }
  __syncthreads();
  #pragma unroll
  for (int p = 0; p < 4; p++){
    int o = p*64 + (t >> 2), c = t & 3;
    float4 v = make_float4(T[c*4+0][o], T[c*4+1][o], T[c*4+2][o], T[c*4+3][o]);
    *(float4*)(out + ((size_t)(b*256 + o))*M_ + m0 + c*4) = v;
  }
}

extern "C" void kernel_launch(void* const* d_in, const int* in_sizes, int n_in,
                              void* d_out, int out_size, void* d_ws, size_t ws_size,
                              hipStream_t stream)
{
  (void)in_sizes; (void)n_in; (void)out_size; (void)ws_size;
  const float* xyz  = (const float*)d_in[0];
  const float* feat = (const float*)d_in[1];
  const int*   inds = (const int*)d_in[2];
  const float* w1 = (const float*)d_in[3];
  const float* b1 = (const float*)d_in[4];
  const float* g1 = (const float*)d_in[5];
  const float* be1= (const float*)d_in[6];
  const float* w2 = (const float*)d_in[7];
  const float* b2 = (const float*)d_in[8];
  const float* g2 = (const float*)d_in[9];
  const float* be2= (const float*)d_in[10];
  const float* w3 = (const float*)d_in[11];
  const float* b3 = (const float*)d_in[12];
  const float* g3 = (const float*)d_in[13];
  const float* be3= (const float*)d_in[14];

  char* ws = (char*)d_ws;
  float* stats = (float*)ws;
  float* s1sum = stats + 0*256;  float* s1sq = stats + 1*256;
  float* s2sum = stats + 2*256;  float* s2sq = stats + 3*256;
  float* s3sum = stats + 4*256;  float* s3sq = stats + 5*256;
  size_t off = 6*256*sizeof(float);
  int* idx = (int*)(ws + off);                off += (size_t)B_*M_*K_*4;
  ushort_t* ftr_t = (ushort_t*)(ws + off);    off += (size_t)B_*N_*C_*2;
  ushort_t* W1b = (ushort_t*)(ws + off);      off += 128*160*2;
  ushort_t* W2b = (ushort_t*)(ws + off);      off += 128*128*2;
  ushort_t* W3b = (ushort_t*)(ws + off);      off += 256*128*2;
  ushort_t* Y1 = (ushort_t*)(ws + off);       off += (size_t)NTOT*128*2;
  ushort_t* Y2 = (ushort_t*)(ws + off);       off += (size_t)NTOT*128*2;
  unsigned int* Ymm = (unsigned int*)(ws + off); off += (size_t)B_*M_*256*4;

  float* new_xyz  = (float*)d_out;
  float* out_feat = (float*)d_out + (size_t)B_*M_*3;

  hipMemsetAsync(stats, 0, 6*256*sizeof(float), stream);
  prep_w_k<<<272, 256, 0, stream>>>(w1, w2, w3, W1b, W2b, W3b);
  transpose_feat_k<<<2048, 256, 0, stream>>>(feat, ftr_t);
  ball_query_k<<<1024, 256, 0, stream>>>(xyz, inds, new_xyz, idx);
  conv1_k<<<2048, 256, 0, stream>>>(xyz, ftr_t, idx, new_xyz, W1b, b1, Y1, s1sum, s1sq);
  convB_k<128,false><<<2048, 256, 0, stream>>>(Y1, W2b, b2, g1, be1, s1sum, s1sq, Y2, nullptr, s2sum, s2sq);
  convB_k<256,true ><<<2048, 256, 0, stream>>>(Y2, W3b, b3, g2, be2, s2sum, s2sq, nullptr, Ymm, s3sum, s3sq);
  finalize_k<<<256, 256, 0, stream>>>(Ymm, g3, be3, s3sum, s3sq, out_feat);
}

// Round 7
// 296.646 us; speedup vs baseline: 1.0914x; 1.0914x over previous
//
#include <hip/hip_runtime.h>

#define B_ 4
#define N_ 16384
#define C_ 128
#define M_ 1024
#define K_ 32
#define NTOT (B_*M_*K_)   /* 131072 */
#define RAD2 0.16f
#define EPS_ 1e-5f

typedef unsigned short ushort_t;
typedef __bf16 bf16x8 __attribute__((ext_vector_type(8)));
typedef float f32x4 __attribute__((ext_vector_type(4)));

__device__ __forceinline__ float b2f(ushort_t u){
  unsigned int x = ((unsigned int)u) << 16;
  return __builtin_bit_cast(float, x);
}
__device__ __forceinline__ ushort_t f2b(float f){
  unsigned int u = __builtin_bit_cast(unsigned int, f);
  unsigned int r = (u + 0x7FFFu + ((u >> 16) & 1u)) >> 16;
  return (ushort_t)r;
}

// ---------------- ball query: 1 wave per query, no LDS, no barriers ---------
__global__ __launch_bounds__(256) void ball_query_k(
    const float* __restrict__ xyz, const int* __restrict__ indices,
    float* __restrict__ new_xyz, int* __restrict__ idx)
{
  int t = threadIdx.x;
  int wv = t >> 6, lane = t & 63;
  int g = blockIdx.x*4 + wv;
  int b = g >> 10;
  const float* pb = xyz + (size_t)b*N_*3;
  const float4* pb4 = (const float4*)pb;
  int qi = indices[g];
  float qx = pb[qi*3+0], qy = pb[qi*3+1], qz = pb[qi*3+2];
  if (lane < 3) new_xyz[g*3 + lane] = pb[qi*3 + lane];

  int cnt = 0, firstIdx = 0;
  int* op = idx + g*K_;

  float4 buf0[6], buf1[6];
  #pragma unroll
  for (int i = 0; i < 6; i++) buf0[i] = pb4[lane*6 + i];

  auto process = [&](const float4* buf, int chunk){
    const float* f = (const float*)buf;
    unsigned int local_mask = 0;
    #pragma unroll
    for (int j = 0; j < 8; j++){
      float dx = f[j*3+0]-qx, dy = f[j*3+1]-qy, dz = f[j*3+2]-qz;
      if (dx*dx + dy*dy + dz*dz < RAD2) local_mask |= (1u << j);
    }
    if (__ballot(local_mask != 0) == 0ull) return;
    int base = chunk*512;
    int lcnt = __popc(local_mask);
    int incl = lcnt;
    #pragma unroll
    for (int d = 1; d < 64; d <<= 1){
      int tt = __shfl_up(incl, d);
      if (lane >= d) incl += tt;
    }
    int excl = incl - lcnt;
    int total = __shfl(incl, 63);
    if (cnt == 0){
      int lf = local_mask ? (lane*8 + __builtin_ctz(local_mask)) : 0x7fffffff;
      #pragma unroll
      for (int d = 1; d < 64; d <<= 1) lf = min(lf, __shfl_xor(lf, d));
      firstIdx = base + lf;
    }
    int sl = cnt + excl;
    unsigned int m = local_mask;
    while (m && sl < K_){
      int j = __builtin_ctz(m); m &= m - 1u;
      op[sl++] = base + lane*8 + j;
    }
    cnt += total;
  };

  for (int chunk = 0; chunk < 32; chunk += 2){
    if (chunk + 1 < 32){
      #pragma unroll
      for (int i = 0; i < 6; i++) buf1[i] = pb4[(chunk+1)*384 + lane*6 + i];
    }
    process(buf0, chunk);
    if (cnt >= K_) break;
    if (chunk + 2 < 32){
      #pragma unroll
      for (int i = 0; i < 6; i++) buf0[i] = pb4[(chunk+2)*384 + lane*6 + i];
    }
    process(buf1, chunk + 1);
    if (cnt >= K_) break;
  }
  if (cnt < K_){
    for (int s = cnt + lane; s < K_; s += 64) op[s] = firstIdx;
  }
}

// ---------------- features (B,C,N) f32 -> (B,N,C) bf16 ----------------------
__global__ __launch_bounds__(256) void transpose_feat_k(
    const float* __restrict__ feat, ushort_t* __restrict__ ftr_t)
{
  __shared__ float T[32][133];
  int bi = blockIdx.x;
  int b = bi >> 9, ntile = bi & 511;
  int n0 = ntile * 32;
  int t = threadIdx.x;
  int nl = t & 31;
  #pragma unroll
  for (int ci = 0; ci < 16; ci++){
    int c = ci*8 + (t >> 5);
    T[nl][c] = feat[((size_t)b*C_ + c)*N_ + n0 + nl];
  }
  __syncthreads();
  #pragma unroll
  for (int ii = 0; ii < 2; ii++){
    int v = ii*256 + t;
    int n2 = v >> 4, seg = v & 15;
    union { ushort_t u[8]; uint4 q; } pk;
    #pragma unroll
    for (int j = 0; j < 8; j++) pk.u[j] = f2b(T[n2][seg*8 + j]);
    *(uint4*)(ftr_t + ((size_t)b*N_ + n0 + n2)*C_ + seg*8) = pk.q;
  }
}

// ---------------- weights f32 -> bf16 (W1 reordered: feat|xyz|0, stride 160) -
__global__ __launch_bounds__(256) void prep_w_k(
    const float* __restrict__ w1, const float* __restrict__ w2, const float* __restrict__ w3,
    ushort_t* __restrict__ W1b, ushort_t* __restrict__ W2b, ushort_t* __restrict__ W3b)
{
  const int T1 = 128*160, T2 = 128*128, T3 = 256*128;
  for (int e = blockIdx.x*256 + threadIdx.x; e < T1+T2+T3; e += gridDim.x*256){
    if (e < T1){
      int o = e / 160, c = e % 160;
      float v = 0.f;
      if (c < 128) v = w1[o*131 + 3 + c];
      else if (c < 131) v = w1[o*131 + (c - 128)];
      W1b[e] = f2b(v);
    } else if (e < T1+T2){
      int e2 = e - T1;
      W2b[e2] = f2b(w2[e2]);
    } else {
      int e3 = e - T1 - T2;
      W3b[e3] = f2b(w3[e3]);
    }
  }
}

// ---------------- conv1: gather (feat|xyzdiff) -> GEMM, W in registers ------
// GPB=4 / grid 1024: 4 blocks/CU (round-6 evidence: GPB=2 prologue-bound,
// GPB=8 grid-capped at 2 blocks/CU). lb(256,4) caps VGPR at 128 (measured 116).
__global__ __launch_bounds__(256, 4) void conv1_k(
    const float* __restrict__ xyz, const ushort_t* __restrict__ ftr_t,
    const int* __restrict__ idx, const float* __restrict__ new_xyz,
    const ushort_t* __restrict__ W1b, const float* __restrict__ b1,
    ushort_t* __restrict__ Y1, float* __restrict__ sumO, float* __restrict__ sqO)
{
  __shared__ alignas(16) ushort_t Xs[32*168];
  __shared__ alignas(16) float Ys[32*132];
  int t = threadIdx.x;
  int wv = t >> 6, lane = t & 63, quad = lane >> 4, l15 = lane & 15;
  int row = t >> 3, chunk = t & 7;

  if (t < 128){
    int rr = t >> 2, cc = t & 3;
    *(uint4*)(Xs + rr*168 + 128 + cc*8) = make_uint4(0,0,0,0);
  }
  bf16x8 wf[2][5];
  #pragma unroll
  for (int nt = 0; nt < 2; nt++)
    #pragma unroll
    for (int kt = 0; kt < 5; kt++)
      wf[nt][kt] = *(const bf16x8*)(W1b + (wv*32 + nt*16 + l15)*160 + kt*32 + quad*8);
  float bs_r[2] = { b1[wv*32 + l15], b1[wv*32 + 16 + l15] };
  float s[2] = {0.f,0.f}, s2[2] = {0.f,0.f};

  const int GPB = 4;
  int g0 = blockIdx.x * GPB;
  for (int i = 0; i < GPB; i++){
    int g = g0 + i;
    int b = g >> 10;
    int n = idx[g*K_ + row];
    const ushort_t* src = ftr_t + ((size_t)b*N_ + n)*C_ + chunk*16;
    uint4 q0 = *(const uint4*)src;
    uint4 q1 = *(const uint4*)(src + 8);
    *(uint4*)(Xs + row*168 + chunk*16) = q0;
    *(uint4*)(Xs + row*168 + chunk*16 + 8) = q1;
    if (t < 32){
      int n2 = idx[g*K_ + t];
      const float* pp = xyz + ((size_t)b*N_ + n2)*3;
      const float* qq = new_xyz + (size_t)g*3;
      unsigned int u0 = (unsigned int)f2b(pp[0]-qq[0]) | ((unsigned int)f2b(pp[1]-qq[1]) << 16);
      unsigned int u1 = (unsigned int)f2b(pp[2]-qq[2]);
      *(uint2*)(Xs + t*168 + 128) = make_uint2(u0, u1);
    }
    __syncthreads();
    bf16x8 af[2][5];
    #pragma unroll
    for (int mt = 0; mt < 2; mt++)
      #pragma unroll
      for (int kt = 0; kt < 5; kt++)
        af[mt][kt] = *(const bf16x8*)(Xs + (mt*16 + l15)*168 + kt*32 + quad*8);
    f32x4 acc[2][2];
    #pragma unroll
    for (int nt = 0; nt < 2; nt++){ acc[nt][0] = (f32x4){0,0,0,0}; acc[nt][1] = (f32x4){0,0,0,0}; }
    #pragma unroll
    for (int nt = 0; nt < 2; nt++)
      #pragma unroll
      for (int kt = 0; kt < 5; kt++){
        acc[nt][0] = __builtin_amdgcn_mfma_f32_16x16x32_bf16(af[0][kt], wf[nt][kt], acc[nt][0], 0,0,0);
        acc[nt][1] = __builtin_amdgcn_mfma_f32_16x16x32_bf16(af[1][kt], wf[nt][kt], acc[nt][1], 0,0,0);
      }
    #pragma unroll
    for (int nt = 0; nt < 2; nt++){
      int o = wv*32 + nt*16 + l15;
      #pragma unroll
      for (int mt = 0; mt < 2; mt++)
        #pragma unroll
        for (int r = 0; r < 4; r++){
          float v = acc[nt][mt][r] + bs_r[nt];
          s[nt] += v; s2[nt] += v*v;
          Ys[(mt*16 + quad*4 + r)*132 + o] = v;
        }
    }
    __syncthreads();
    {
      const float* yp = &Ys[row*132 + chunk*16];
      f32x4 y0 = *(const f32x4*)(yp);
      f32x4 y1 = *(const f32x4*)(yp + 4);
      f32x4 y2 = *(const f32x4*)(yp + 8);
      f32x4 y3 = *(const f32x4*)(yp + 12);
      union { ushort_t u[8]; uint4 q; } p0, p1;
      #pragma unroll
      for (int j = 0; j < 4; j++){
        p0.u[j] = f2b(y0[j]); p0.u[4+j] = f2b(y1[j]);
        p1.u[j] = f2b(y2[j]); p1.u[4+j] = f2b(y3[j]);
      }
      ushort_t* dst = Y1 + ((size_t)g*K_ + row)*128 + chunk*16;
      *(uint4*)dst = p0.q;
      *(uint4*)(dst + 8) = p1.q;
    }
  }
  #pragma unroll
  for (int nt = 0; nt < 2; nt++){
    s[nt]  += __shfl_xor(s[nt], 16);  s[nt]  += __shfl_xor(s[nt], 32);
    s2[nt] += __shfl_xor(s2[nt], 16); s2[nt] += __shfl_xor(s2[nt], 32);
    if (quad == 0){
      int o = wv*32 + nt*16 + l15;
      atomicAdd(&sumO[o], s[nt]);
      atomicAdd(&sqO[o], s2[nt]);
    }
  }
}

// ---------------- conv2/conv3: BN(prev)+relu staging, W in registers --------
// MAXMIN (conv3): Xs double-buffered -> single barrier per group.
template<int COUT, bool MAXMIN>
__global__ __launch_bounds__(256, 4) void convB_k(
    const ushort_t* __restrict__ Yin, const ushort_t* __restrict__ Wb,
    const float* __restrict__ bias, const float* __restrict__ g_bn,
    const float* __restrict__ beta_bn, const float* __restrict__ sumI,
    const float* __restrict__ sqI, ushort_t* __restrict__ Yout,
    unsigned int* __restrict__ Ymm, float* __restrict__ sumO, float* __restrict__ sqO)
{
  constexpr int NT = COUT/64;
  constexpr int NXS = MAXMIN ? 2 : 1;
  __shared__ alignas(16) ushort_t Xs[NXS][32*136];
  __shared__ alignas(16) float Ys[MAXMIN ? 4 : 32*132];
  int t = threadIdx.x;
  int wv = t >> 6, lane = t & 63, quad = lane >> 4, l15 = lane & 15;
  int row = t >> 3, chunk = t & 7;

  float a_r[16], d_r[16];
  #pragma unroll
  for (int j = 0; j < 16; j++){
    int c = chunk*16 + j;
    float mu  = sumI[c] * (1.f/NTOT);
    float var = sqI[c]  * (1.f/NTOT) - mu*mu;
    float a = g_bn[c] * rsqrtf(var + EPS_);
    a_r[j] = a; d_r[j] = beta_bn[c] - a*mu;
  }
  bf16x8 wf[NT][4];
  #pragma unroll
  for (int nt = 0; nt < NT; nt++)
    #pragma unroll
    for (int kt = 0; kt < 4; kt++)
      wf[nt][kt] = *(const bf16x8*)(Wb + (wv*(NT*16) + nt*16 + l15)*128 + kt*32 + quad*8);
  float bs_r[NT];
  #pragma unroll
  for (int nt = 0; nt < NT; nt++) bs_r[nt] = bias[wv*(NT*16) + nt*16 + l15];
  float s[NT], s2[NT];
  #pragma unroll
  for (int nt = 0; nt < NT; nt++){ s[nt] = 0.f; s2[nt] = 0.f; }

  const int GPB = 4;
  int g0 = blockIdx.x * GPB;
  uint4 r0, r1;
  {
    const ushort_t* src = Yin + ((size_t)g0*K_ + row)*128 + chunk*16;
    r0 = *(const uint4*)src; r1 = *(const uint4*)(src + 8);
  }
  for (int i = 0; i < GPB; i++){
    int g = g0 + i;
    ushort_t* X = Xs[MAXMIN ? (i & (NXS-1)) : 0];
    union { ushort_t u[8]; uint4 q; } i0, i1, o0, o1;
    i0.q = r0; i1.q = r1;
    #pragma unroll
    for (int j = 0; j < 8; j++){
      o0.u[j] = f2b(fmaxf(a_r[j]  *b2f(i0.u[j]) + d_r[j],   0.f));
      o1.u[j] = f2b(fmaxf(a_r[8+j]*b2f(i1.u[j]) + d_r[8+j], 0.f));
    }
    *(uint4*)(X + row*136 + chunk*16) = o0.q;
    *(uint4*)(X + row*136 + chunk*16 + 8) = o1.q;
    if (i + 1 < GPB){
      const ushort_t* src = Yin + ((size_t)(g+1)*K_ + row)*128 + chunk*16;
      r0 = *(const uint4*)src; r1 = *(const uint4*)(src + 8);
    }
    __syncthreads();
    bf16x8 af[2][4];
    #pragma unroll
    for (int mt = 0; mt < 2; mt++)
      #pragma unroll
      for (int kt = 0; kt < 4; kt++)
        af[mt][kt] = *(const bf16x8*)(X + (mt*16 + l15)*136 + kt*32 + quad*8);
    f32x4 acc[NT][2];
    #pragma unroll
    for (int nt = 0; nt < NT; nt++){ acc[nt][0] = (f32x4){0,0,0,0}; acc[nt][1] = (f32x4){0,0,0,0}; }
    #pragma unroll
    for (int nt = 0; nt < NT; nt++)
      #pragma unroll
      for (int kt = 0; kt < 4; kt++){
        acc[nt][0] = __builtin_amdgcn_mfma_f32_16x16x32_bf16(af[0][kt], wf[nt][kt], acc[nt][0], 0,0,0);
        acc[nt][1] = __builtin_amdgcn_mfma_f32_16x16x32_bf16(af[1][kt], wf[nt][kt], acc[nt][1], 0,0,0);
      }
    if constexpr (!MAXMIN){
      #pragma unroll
      for (int nt = 0; nt < NT; nt++){
        int o = wv*(NT*16) + nt*16 + l15;
        #pragma unroll
        for (int mt = 0; mt < 2; mt++)
          #pragma unroll
          for (int r = 0; r < 4; r++){
            float v = acc[nt][mt][r] + bs_r[nt];
            s[nt] += v; s2[nt] += v*v;
            Ys[(mt*16 + quad*4 + r)*132 + o] = v;
          }
      }
      __syncthreads();
      const float* yp = &Ys[row*132 + chunk*16];
      f32x4 y0 = *(const f32x4*)(yp);
      f32x4 y1 = *(const f32x4*)(yp + 4);
      f32x4 y2 = *(const f32x4*)(yp + 8);
      f32x4 y3 = *(const f32x4*)(yp + 12);
      union { ushort_t u[8]; uint4 q; } p0, p1;
      #pragma unroll
      for (int j = 0; j < 4; j++){
        p0.u[j] = f2b(y0[j]); p0.u[4+j] = f2b(y1[j]);
        p1.u[j] = f2b(y2[j]); p1.u[4+j] = f2b(y3[j]);
      }
      ushort_t* dst = Yout + ((size_t)g*K_ + row)*128 + chunk*16;
      *(uint4*)dst = p0.q;
      *(uint4*)(dst + 8) = p1.q;
    } else {
      #pragma unroll
      for (int nt = 0; nt < NT; nt++){
        float v0 = acc[nt][0][0] + bs_r[nt];
        float mx = v0, mn = v0;
        s[nt] += v0; s2[nt] += v0*v0;
        #pragma unroll
        for (int mt = 0; mt < 2; mt++)
          #pragma unroll
          for (int r = 0; r < 4; r++){
            if (mt == 0 && r == 0) continue;
            float v = acc[nt][mt][r] + bs_r[nt];
            s[nt] += v; s2[nt] += v*v;
            mx = fmaxf(mx, v); mn = fminf(mn, v);
          }
        mx = fmaxf(mx, __shfl_xor(mx, 16)); mx = fmaxf(mx, __shfl_xor(mx, 32));
        mn = fminf(mn, __shfl_xor(mn, 16)); mn = fminf(mn, __shfl_xor(mn, 32));
        if (quad == 0){
          int o = wv*64 + nt*16 + l15;
          Ymm[(size_t)g*256 + o] = (unsigned int)f2b(mx) | ((unsigned int)f2b(mn) << 16);
        }
      }
      // no trailing barrier: next iteration writes the other Xs buffer
    }
  }
  #pragma unroll
  for (int nt = 0; nt < NT; nt++){
    s[nt]  += __shfl_xor(s[nt], 16);  s[nt]  += __shfl_xor(s[nt], 32);
    s2[nt] += __shfl_xor(s2[nt], 16); s2[nt] += __shfl_xor(s2[nt], 32);
    if (quad == 0){
      int o = wv*(NT*16) + nt*16 + l15;
      atomicAdd(&sumO[o], s[nt]);
      atomicAdd(&sqO[o], s2[nt]);
    }
  }
}

// ---------------- finalize: BN3 from max/min pairs, transposed store --------
__global__ __launch_bounds__(256) void finalize_k(
    const unsigned int* __restrict__ Ymm, const float* __restrict__ g3,
    const float* __restrict__ beta3, const float* __restrict__ sum3,
    const float* __restrict__ sq3, float* __restrict__ out)
{
  __shared__ float T[16][264];
  __shared__ float abn[256], dbn[256];
  int t = threadIdx.x;
  int b = blockIdx.x >> 6;
  int m0 = (blockIdx.x & 63) * 16;
  {
    float mu  = sum3[t] * (1.f/NTOT);
    float var = sq3[t]  * (1.f/NTOT) - mu*mu;
    float a = g3[t] * rsqrtf(var + EPS_);
    abn[t] = a; dbn[t] = beta3[t] - a*mu;
  }
  __syncthreads();
  #pragma unroll
  for (int i = 0; i < 4; i++){
    int v4 = i*256 + t;
    int m = v4 >> 6, oq = (v4 & 63) * 4;
    uint4 w = *(const uint4*)(Ymm + ((size_t)(b*M_ + m0 + m))*256 + oq);
    unsigned int wsv[4] = {w.x, w.y, w.z, w.w};
    float r[4];
    #pragma unroll
    for (int j = 0; j < 4; j++){
      int o = oq + j;
      float mx = b2f((ushort_t)(wsv[j] & 0xffffu));
      float mn = b2f((ushort_t)(wsv[j] >> 16));
      float a = abn[o];
      float val = (a >= 0.f) ? (a*mx + dbn[o]) : (a*mn + dbn[o]);
      r[j] = fmaxf(val, 0.f);
    }
    *(f32x4*)(&T[m][oq]) = *(f32x4*)r;
  }
  __syncthreads();
  #pragma unroll
  for (int p = 0; p < 4; p++){
    int o = p*64 + (t >> 2), c = t & 3;
    float4 v = make_float4(T[c*4+0][o], T[c*4+1][o], T[c*4+2][o], T[c*4+3][o]);
    *(float4*)(out + ((size_t)(b*256 + o))*M_ + m0 + c*4) = v;
  }
}

extern "C" void kernel_launch(void* const* d_in, const int* in_sizes, int n_in,
                              void* d_out, int out_size, void* d_ws, size_t ws_size,
                              hipStream_t stream)
{
  (void)in_sizes; (void)n_in; (void)out_size; (void)ws_size;
  const float* xyz  = (const float*)d_in[0];
  const float* feat = (const float*)d_in[1];
  const int*   inds = (const int*)d_in[2];
  const float* w1 = (const float*)d_in[3];
  const float* b1 = (const float*)d_in[4];
  const float* g1 = (const float*)d_in[5];
  const float* be1= (const float*)d_in[6];
  const float* w2 = (const float*)d_in[7];
  const float* b2 = (const float*)d_in[8];
  const float* g2 = (const float*)d_in[9];
  const float* be2= (const float*)d_in[10];
  const float* w3 = (const float*)d_in[11];
  const float* b3 = (const float*)d_in[12];
  const float* g3 = (const float*)d_in[13];
  const float* be3= (const float*)d_in[14];

  char* ws = (char*)d_ws;
  float* stats = (float*)ws;
  float* s1sum = stats + 0*256;  float* s1sq = stats + 1*256;
  float* s2sum = stats + 2*256;  float* s2sq = stats + 3*256;
  float* s3sum = stats + 4*256;  float* s3sq = stats + 5*256;
  size_t off = 6*256*sizeof(float);
  int* idx = (int*)(ws + off);                off += (size_t)B_*M_*K_*4;
  ushort_t* ftr_t = (ushort_t*)(ws + off);    off += (size_t)B_*N_*C_*2;
  ushort_t* W1b = (ushort_t*)(ws + off);      off += 128*160*2;
  ushort_t* W2b = (ushort_t*)(ws + off);      off += 128*128*2;
  ushort_t* W3b = (ushort_t*)(ws + off);      off += 256*128*2;
  ushort_t* Y1 = (ushort_t*)(ws + off);       off += (size_t)NTOT*128*2;
  ushort_t* Y2 = (ushort_t*)(ws + off);       off += (size_t)NTOT*128*2;
  unsigned int* Ymm = (unsigned int*)(ws + off); off += (size_t)B_*M_*256*4;

  float* new_xyz  = (float*)d_out;
  float* out_feat = (float*)d_out + (size_t)B_*M_*3;

  hipMemsetAsync(stats, 0, 6*256*sizeof(float), stream);
  prep_w_k<<<272, 256, 0, stream>>>(w1, w2, w3, W1b, W2b, W3b);
  transpose_feat_k<<<2048, 256, 0, stream>>>(feat, ftr_t);
  ball_query_k<<<1024, 256, 0, stream>>>(xyz, inds, new_xyz, idx);
  conv1_k<<<1024, 256, 0, stream>>>(xyz, ftr_t, idx, new_xyz, W1b, b1, Y1, s1sum, s1sq);
  convB_k<128,false><<<1024, 256, 0, stream>>>(Y1, W2b, b2, g1, be1, s1sum, s1sq, Y2, nullptr, s2sum, s2sq);
  convB_k<256,true ><<<1024, 256, 0, stream>>>(Y2, W3b, b3, g2, be2, s2sum, s2sq, nullptr, Ymm, s3sum, s3sq);
  finalize_k<<<256, 256, 0, stream>>>(Ymm, g3, be3, s3sum, s3sq, out_feat);
}

// Round 8
// 225.034 us; speedup vs baseline: 1.4387x; 1.3182x over previous
//
#include <hip/hip_runtime.h>

#define B_ 4
#define N_ 16384
#define C_ 128
#define M_ 1024
#define K_ 32
#define NTOT (B_*M_*K_)   /* 131072 */
#define RAD2 0.16f
#define EPS_ 1e-5f

typedef unsigned short ushort_t;
typedef __bf16 bf16x8 __attribute__((ext_vector_type(8)));
typedef float f32x4 __attribute__((ext_vector_type(4)));

__device__ __forceinline__ float b2f(ushort_t u){
  unsigned int x = ((unsigned int)u) << 16;
  return __builtin_bit_cast(float, x);
}
__device__ __forceinline__ ushort_t f2b(float f){
  unsigned int u = __builtin_bit_cast(unsigned int, f);
  unsigned int r = (u + 0x7FFFu + ((u >> 16) & 1u)) >> 16;
  return (ushort_t)r;
}

// ---------------- ball query: 1 wave per query, no LDS, no barriers ---------
__global__ __launch_bounds__(256) void ball_query_k(
    const float* __restrict__ xyz, const int* __restrict__ indices,
    float* __restrict__ new_xyz, int* __restrict__ idx)
{
  int t = threadIdx.x;
  int wv = t >> 6, lane = t & 63;
  int g = blockIdx.x*4 + wv;
  int b = g >> 10;
  const float* pb = xyz + (size_t)b*N_*3;
  const float4* pb4 = (const float4*)pb;
  int qi = indices[g];
  float qx = pb[qi*3+0], qy = pb[qi*3+1], qz = pb[qi*3+2];
  if (lane < 3) new_xyz[g*3 + lane] = pb[qi*3 + lane];

  int cnt = 0, firstIdx = 0;
  int* op = idx + g*K_;

  float4 buf0[6], buf1[6];
  #pragma unroll
  for (int i = 0; i < 6; i++) buf0[i] = pb4[lane*6 + i];

  auto process = [&](const float4* buf, int chunk){
    const float* f = (const float*)buf;
    unsigned int local_mask = 0;
    #pragma unroll
    for (int j = 0; j < 8; j++){
      float dx = f[j*3+0]-qx, dy = f[j*3+1]-qy, dz = f[j*3+2]-qz;
      if (dx*dx + dy*dy + dz*dz < RAD2) local_mask |= (1u << j);
    }
    if (__ballot(local_mask != 0) == 0ull) return;
    int base = chunk*512;
    int lcnt = __popc(local_mask);
    int incl = lcnt;
    #pragma unroll
    for (int d = 1; d < 64; d <<= 1){
      int tt = __shfl_up(incl, d);
      if (lane >= d) incl += tt;
    }
    int excl = incl - lcnt;
    int total = __shfl(incl, 63);
    if (cnt == 0){
      int lf = local_mask ? (lane*8 + __builtin_ctz(local_mask)) : 0x7fffffff;
      #pragma unroll
      for (int d = 1; d < 64; d <<= 1) lf = min(lf, __shfl_xor(lf, d));
      firstIdx = base + lf;
    }
    int sl = cnt + excl;
    unsigned int m = local_mask;
    while (m && sl < K_){
      int j = __builtin_ctz(m); m &= m - 1u;
      op[sl++] = base + lane*8 + j;
    }
    cnt += total;
  };

  for (int chunk = 0; chunk < 32; chunk += 2){
    if (chunk + 1 < 32){
      #pragma unroll
      for (int i = 0; i < 6; i++) buf1[i] = pb4[(chunk+1)*384 + lane*6 + i];
    }
    process(buf0, chunk);
    if (cnt >= K_) break;
    if (chunk + 2 < 32){
      #pragma unroll
      for (int i = 0; i < 6; i++) buf0[i] = pb4[(chunk+2)*384 + lane*6 + i];
    }
    process(buf1, chunk + 1);
    if (cnt >= K_) break;
  }
  if (cnt < K_){
    for (int s = cnt + lane; s < K_; s += 64) op[s] = firstIdx;
  }
}

// ---------------- features (B,C,N) f32 -> (B,N,C) bf16 ----------------------
__global__ __launch_bounds__(256) void transpose_feat_k(
    const float* __restrict__ feat, ushort_t* __restrict__ ftr_t)
{
  __shared__ float T[32][133];
  int bi = blockIdx.x;
  int b = bi >> 9, ntile = bi & 511;
  int n0 = ntile * 32;
  int t = threadIdx.x;
  int nl = t & 31;
  #pragma unroll
  for (int ci = 0; ci < 16; ci++){
    int c = ci*8 + (t >> 5);
    T[nl][c] = feat[((size_t)b*C_ + c)*N_ + n0 + nl];
  }
  __syncthreads();
  #pragma unroll
  for (int ii = 0; ii < 2; ii++){
    int v = ii*256 + t;
    int n2 = v >> 4, seg = v & 15;
    union { ushort_t u[8]; uint4 q; } pk;
    #pragma unroll
    for (int j = 0; j < 8; j++) pk.u[j] = f2b(T[n2][seg*8 + j]);
    *(uint4*)(ftr_t + ((size_t)b*N_ + n0 + n2)*C_ + seg*8) = pk.q;
  }
}

// ---------------- weights f32 -> bf16 (W1 reordered: feat|xyz|0, stride 160) -
__global__ __launch_bounds__(256) void prep_w_k(
    const float* __restrict__ w1, const float* __restrict__ w2, const float* __restrict__ w3,
    ushort_t* __restrict__ W1b, ushort_t* __restrict__ W2b, ushort_t* __restrict__ W3b)
{
  const int T1 = 128*160, T2 = 128*128, T3 = 256*128;
  for (int e = blockIdx.x*256 + threadIdx.x; e < T1+T2+T3; e += gridDim.x*256){
    if (e < T1){
      int o = e / 160, c = e % 160;
      float v = 0.f;
      if (c < 128) v = w1[o*131 + 3 + c];
      else if (c < 131) v = w1[o*131 + (c - 128)];
      W1b[e] = f2b(v);
    } else if (e < T1+T2){
      int e2 = e - T1;
      W2b[e2] = f2b(w2[e2]);
    } else {
      int e3 = e - T1 - T2;
      W3b[e3] = f2b(w3[e3]);
    }
  }
}

// ---------------- conv1: gather (feat|xyzdiff) -> GEMM, W in registers ------
// Round-4 config (GPB=8, grid 512, lb(256,2)) — the measured 227 µs anchor.
// r6/r7 lesson: forcing occupancy (lb 3/4) either starves amortization or
// spills (r7: VGPR 64, scratch blew FETCH to 142 MB). Do not cap registers.
__global__ __launch_bounds__(256, 2) void conv1_k(
    const float* __restrict__ xyz, const ushort_t* __restrict__ ftr_t,
    const int* __restrict__ idx, const float* __restrict__ new_xyz,
    const ushort_t* __restrict__ W1b, const float* __restrict__ b1,
    ushort_t* __restrict__ Y1, float* __restrict__ sumO, float* __restrict__ sqO)
{
  __shared__ alignas(16) ushort_t Xs[32*168];
  __shared__ alignas(16) float Ys[32*132];
  int t = threadIdx.x;
  int wv = t >> 6, lane = t & 63, quad = lane >> 4, l15 = lane & 15;
  int row = t >> 3, chunk = t & 7;

  if (t < 128){
    int rr = t >> 2, cc = t & 3;
    *(uint4*)(Xs + rr*168 + 128 + cc*8) = make_uint4(0,0,0,0);
  }
  bf16x8 wf[2][5];
  #pragma unroll
  for (int nt = 0; nt < 2; nt++)
    #pragma unroll
    for (int kt = 0; kt < 5; kt++)
      wf[nt][kt] = *(const bf16x8*)(W1b + (wv*32 + nt*16 + l15)*160 + kt*32 + quad*8);
  float bs_r[2] = { b1[wv*32 + l15], b1[wv*32 + 16 + l15] };
  float s[2] = {0.f,0.f}, s2[2] = {0.f,0.f};

  const int GPB = 8;
  int g0 = blockIdx.x * GPB;
  int b = g0 >> 10;                    // GPB=8 divides 1024: same batch per block
  // hoist idx loads: removes idx->gather address chain from each group's path
  int ia[GPB], ibv[GPB];
  #pragma unroll
  for (int i = 0; i < GPB; i++){
    ia[i]  = idx[(g0+i)*K_ + row];
    ibv[i] = idx[(g0+i)*K_ + (t & 31)];
  }
  for (int i = 0; i < GPB; i++){
    int g = g0 + i;
    const ushort_t* src = ftr_t + ((size_t)b*N_ + ia[i])*C_ + chunk*16;
    uint4 q0 = *(const uint4*)src;
    uint4 q1 = *(const uint4*)(src + 8);
    *(uint4*)(Xs + row*168 + chunk*16) = q0;
    *(uint4*)(Xs + row*168 + chunk*16 + 8) = q1;
    if (t < 32){
      const float* pp = xyz + ((size_t)b*N_ + ibv[i])*3;
      const float* qq = new_xyz + (size_t)g*3;
      unsigned int u0 = (unsigned int)f2b(pp[0]-qq[0]) | ((unsigned int)f2b(pp[1]-qq[1]) << 16);
      unsigned int u1 = (unsigned int)f2b(pp[2]-qq[2]);
      *(uint2*)(Xs + t*168 + 128) = make_uint2(u0, u1);
    }
    __syncthreads();
    bf16x8 af[2][5];
    #pragma unroll
    for (int mt = 0; mt < 2; mt++)
      #pragma unroll
      for (int kt = 0; kt < 5; kt++)
        af[mt][kt] = *(const bf16x8*)(Xs + (mt*16 + l15)*168 + kt*32 + quad*8);
    f32x4 acc[2][2];
    #pragma unroll
    for (int nt = 0; nt < 2; nt++){ acc[nt][0] = (f32x4){0,0,0,0}; acc[nt][1] = (f32x4){0,0,0,0}; }
    #pragma unroll
    for (int nt = 0; nt < 2; nt++)
      #pragma unroll
      for (int kt = 0; kt < 5; kt++){
        acc[nt][0] = __builtin_amdgcn_mfma_f32_16x16x32_bf16(af[0][kt], wf[nt][kt], acc[nt][0], 0,0,0);
        acc[nt][1] = __builtin_amdgcn_mfma_f32_16x16x32_bf16(af[1][kt], wf[nt][kt], acc[nt][1], 0,0,0);
      }
    #pragma unroll
    for (int nt = 0; nt < 2; nt++){
      int o = wv*32 + nt*16 + l15;
      #pragma unroll
      for (int mt = 0; mt < 2; mt++)
        #pragma unroll
        for (int r = 0; r < 4; r++){
          float v = acc[nt][mt][r] + bs_r[nt];
          s[nt] += v; s2[nt] += v*v;
          Ys[(mt*16 + quad*4 + r)*132 + o] = v;
        }
    }
    __syncthreads();
    {
      const float* yp = &Ys[row*132 + chunk*16];
      f32x4 y0 = *(const f32x4*)(yp);
      f32x4 y1 = *(const f32x4*)(yp + 4);
      f32x4 y2 = *(const f32x4*)(yp + 8);
      f32x4 y3 = *(const f32x4*)(yp + 12);
      union { ushort_t u[8]; uint4 q; } p0, p1;
      #pragma unroll
      for (int j = 0; j < 4; j++){
        p0.u[j] = f2b(y0[j]); p0.u[4+j] = f2b(y1[j]);
        p1.u[j] = f2b(y2[j]); p1.u[4+j] = f2b(y3[j]);
      }
      ushort_t* dst = Y1 + ((size_t)g*K_ + row)*128 + chunk*16;
      *(uint4*)dst = p0.q;
      *(uint4*)(dst + 8) = p1.q;
    }
  }
  #pragma unroll
  for (int nt = 0; nt < 2; nt++){
    s[nt]  += __shfl_xor(s[nt], 16);  s[nt]  += __shfl_xor(s[nt], 32);
    s2[nt] += __shfl_xor(s2[nt], 16); s2[nt] += __shfl_xor(s2[nt], 32);
    if (quad == 0){
      int o = wv*32 + nt*16 + l15;
      atomicAdd(&sumO[o], s[nt]);
      atomicAdd(&sqO[o], s2[nt]);
    }
  }
}

// ---------------- conv2/conv3: BN(prev)+relu staging, W in registers --------
// MAXMIN (conv3): Xs double-buffered -> single barrier per group.
template<int COUT, bool MAXMIN>
__global__ __launch_bounds__(256, 2) void convB_k(
    const ushort_t* __restrict__ Yin, const ushort_t* __restrict__ Wb,
    const float* __restrict__ bias, const float* __restrict__ g_bn,
    const float* __restrict__ beta_bn, const float* __restrict__ sumI,
    const float* __restrict__ sqI, ushort_t* __restrict__ Yout,
    unsigned int* __restrict__ Ymm, float* __restrict__ sumO, float* __restrict__ sqO)
{
  constexpr int NT = COUT/64;
  constexpr int NXS = MAXMIN ? 2 : 1;
  __shared__ alignas(16) ushort_t Xs[NXS][32*136];
  __shared__ alignas(16) float Ys[MAXMIN ? 4 : 32*132];
  int t = threadIdx.x;
  int wv = t >> 6, lane = t & 63, quad = lane >> 4, l15 = lane & 15;
  int row = t >> 3, chunk = t & 7;

  float a_r[16], d_r[16];
  #pragma unroll
  for (int j = 0; j < 16; j++){
    int c = chunk*16 + j;
    float mu  = sumI[c] * (1.f/NTOT);
    float var = sqI[c]  * (1.f/NTOT) - mu*mu;
    float a = g_bn[c] * rsqrtf(var + EPS_);
    a_r[j] = a; d_r[j] = beta_bn[c] - a*mu;
  }
  bf16x8 wf[NT][4];
  #pragma unroll
  for (int nt = 0; nt < NT; nt++)
    #pragma unroll
    for (int kt = 0; kt < 4; kt++)
      wf[nt][kt] = *(const bf16x8*)(Wb + (wv*(NT*16) + nt*16 + l15)*128 + kt*32 + quad*8);
  float bs_r[NT];
  #pragma unroll
  for (int nt = 0; nt < NT; nt++) bs_r[nt] = bias[wv*(NT*16) + nt*16 + l15];
  float s[NT], s2[NT];
  #pragma unroll
  for (int nt = 0; nt < NT; nt++){ s[nt] = 0.f; s2[nt] = 0.f; }

  const int GPB = 8;
  int g0 = blockIdx.x * GPB;
  uint4 r0, r1;
  {
    const ushort_t* src = Yin + ((size_t)g0*K_ + row)*128 + chunk*16;
    r0 = *(const uint4*)src; r1 = *(const uint4*)(src + 8);
  }
  for (int i = 0; i < GPB; i++){
    int g = g0 + i;
    ushort_t* X = Xs[MAXMIN ? (i & (NXS-1)) : 0];
    union { ushort_t u[8]; uint4 q; } i0, i1, o0, o1;
    i0.q = r0; i1.q = r1;
    #pragma unroll
    for (int j = 0; j < 8; j++){
      o0.u[j] = f2b(fmaxf(a_r[j]  *b2f(i0.u[j]) + d_r[j],   0.f));
      o1.u[j] = f2b(fmaxf(a_r[8+j]*b2f(i1.u[j]) + d_r[8+j], 0.f));
    }
    *(uint4*)(X + row*136 + chunk*16) = o0.q;
    *(uint4*)(X + row*136 + chunk*16 + 8) = o1.q;
    if (i + 1 < GPB){
      const ushort_t* src = Yin + ((size_t)(g+1)*K_ + row)*128 + chunk*16;
      r0 = *(const uint4*)src; r1 = *(const uint4*)(src + 8);
    }
    __syncthreads();
    bf16x8 af[2][4];
    #pragma unroll
    for (int mt = 0; mt < 2; mt++)
      #pragma unroll
      for (int kt = 0; kt < 4; kt++)
        af[mt][kt] = *(const bf16x8*)(X + (mt*16 + l15)*136 + kt*32 + quad*8);
    f32x4 acc[NT][2];
    #pragma unroll
    for (int nt = 0; nt < NT; nt++){ acc[nt][0] = (f32x4){0,0,0,0}; acc[nt][1] = (f32x4){0,0,0,0}; }
    #pragma unroll
    for (int nt = 0; nt < NT; nt++)
      #pragma unroll
      for (int kt = 0; kt < 4; kt++){
        acc[nt][0] = __builtin_amdgcn_mfma_f32_16x16x32_bf16(af[0][kt], wf[nt][kt], acc[nt][0], 0,0,0);
        acc[nt][1] = __builtin_amdgcn_mfma_f32_16x16x32_bf16(af[1][kt], wf[nt][kt], acc[nt][1], 0,0,0);
      }
    if constexpr (!MAXMIN){
      #pragma unroll
      for (int nt = 0; nt < NT; nt++){
        int o = wv*(NT*16) + nt*16 + l15;
        #pragma unroll
        for (int mt = 0; mt < 2; mt++)
          #pragma unroll
          for (int r = 0; r < 4; r++){
            float v = acc[nt][mt][r] + bs_r[nt];
            s[nt] += v; s2[nt] += v*v;
            Ys[(mt*16 + quad*4 + r)*132 + o] = v;
          }
      }
      __syncthreads();
      const float* yp = &Ys[row*132 + chunk*16];
      f32x4 y0 = *(const f32x4*)(yp);
      f32x4 y1 = *(const f32x4*)(yp + 4);
      f32x4 y2 = *(const f32x4*)(yp + 8);
      f32x4 y3 = *(const f32x4*)(yp + 12);
      union { ushort_t u[8]; uint4 q; } p0, p1;
      #pragma unroll
      for (int j = 0; j < 4; j++){
        p0.u[j] = f2b(y0[j]); p0.u[4+j] = f2b(y1[j]);
        p1.u[j] = f2b(y2[j]); p1.u[4+j] = f2b(y3[j]);
      }
      ushort_t* dst = Yout + ((size_t)g*K_ + row)*128 + chunk*16;
      *(uint4*)dst = p0.q;
      *(uint4*)(dst + 8) = p1.q;
    } else {
      #pragma unroll
      for (int nt = 0; nt < NT; nt++){
        float v0 = acc[nt][0][0] + bs_r[nt];
        float mx = v0, mn = v0;
        s[nt] += v0; s2[nt] += v0*v0;
        #pragma unroll
        for (int mt = 0; mt < 2; mt++)
          #pragma unroll
          for (int r = 0; r < 4; r++){
            if (mt == 0 && r == 0) continue;
            float v = acc[nt][mt][r] + bs_r[nt];
            s[nt] += v; s2[nt] += v*v;
            mx = fmaxf(mx, v); mn = fminf(mn, v);
          }
        mx = fmaxf(mx, __shfl_xor(mx, 16)); mx = fmaxf(mx, __shfl_xor(mx, 32));
        mn = fminf(mn, __shfl_xor(mn, 16)); mn = fminf(mn, __shfl_xor(mn, 32));
        if (quad == 0){
          int o = wv*64 + nt*16 + l15;
          Ymm[(size_t)g*256 + o] = (unsigned int)f2b(mx) | ((unsigned int)f2b(mn) << 16);
        }
      }
      // no trailing barrier: next iteration writes the other Xs buffer
    }
  }
  #pragma unroll
  for (int nt = 0; nt < NT; nt++){
    s[nt]  += __shfl_xor(s[nt], 16);  s[nt]  += __shfl_xor(s[nt], 32);
    s2[nt] += __shfl_xor(s2[nt], 16); s2[nt] += __shfl_xor(s2[nt], 32);
    if (quad == 0){
      int o = wv*(NT*16) + nt*16 + l15;
      atomicAdd(&sumO[o], s[nt]);
      atomicAdd(&sqO[o], s2[nt]);
    }
  }
}

// ---------------- finalize: BN3 from max/min pairs, transposed store --------
__global__ __launch_bounds__(256) void finalize_k(
    const unsigned int* __restrict__ Ymm, const float* __restrict__ g3,
    const float* __restrict__ beta3, const float* __restrict__ sum3,
    const float* __restrict__ sq3, float* __restrict__ out)
{
  __shared__ float T[16][264];
  __shared__ float abn[256], dbn[256];
  int t = threadIdx.x;
  int b = blockIdx.x >> 6;
  int m0 = (blockIdx.x & 63) * 16;
  {
    float mu  = sum3[t] * (1.f/NTOT);
    float var = sq3[t]  * (1.f/NTOT) - mu*mu;
    float a = g3[t] * rsqrtf(var + EPS_);
    abn[t] = a; dbn[t] = beta3[t] - a*mu;
  }
  __syncthreads();
  #pragma unroll
  for (int i = 0; i < 4; i++){
    int v4 = i*256 + t;
    int m = v4 >> 6, oq = (v4 & 63) * 4;
    uint4 w = *(const uint4*)(Ymm + ((size_t)(b*M_ + m0 + m))*256 + oq);
    unsigned int wsv[4] = {w.x, w.y, w.z, w.w};
    float r[4];
    #pragma unroll
    for (int j = 0; j < 4; j++){
      int o = oq + j;
      float mx = b2f((ushort_t)(wsv[j] & 0xffffu));
      float mn = b2f((ushort_t)(wsv[j] >> 16));
      float a = abn[o];
      float val = (a >= 0.f) ? (a*mx + dbn[o]) : (a*mn + dbn[o]);
      r[j] = fmaxf(val, 0.f);
    }
    *(f32x4*)(&T[m][oq]) = *(f32x4*)r;
  }
  __syncthreads();
  #pragma unroll
  for (int p = 0; p < 4; p++){
    int o = p*64 + (t >> 2), c = t & 3;
    float4 v = make_float4(T[c*4+0][o], T[c*4+1][o], T[c*4+2][o], T[c*4+3][o]);
    *(float4*)(out + ((size_t)(b*256 + o))*M_ + m0 + c*4) = v;
  }
}

extern "C" void kernel_launch(void* const* d_in, const int* in_sizes, int n_in,
                              void* d_out, int out_size, void* d_ws, size_t ws_size,
                              hipStream_t stream)
{
  (void)in_sizes; (void)n_in; (void)out_size; (void)ws_size;
  const float* xyz  = (const float*)d_in[0];
  const float* feat = (const float*)d_in[1];
  const int*   inds = (const int*)d_in[2];
  const float* w1 = (const float*)d_in[3];
  const float* b1 = (const float*)d_in[4];
  const float* g1 = (const float*)d_in[5];
  const float* be1= (const float*)d_in[6];
  const float* w2 = (const float*)d_in[7];
  const float* b2 = (const float*)d_in[8];
  const float* g2 = (const float*)d_in[9];
  const float* be2= (const float*)d_in[10];
  const float* w3 = (const float*)d_in[11];
  const float* b3 = (const float*)d_in[12];
  const float* g3 = (const float*)d_in[13];
  const float* be3= (const float*)d_in[14];

  char* ws = (char*)d_ws;
  float* stats = (float*)ws;
  float* s1sum = stats + 0*256;  float* s1sq = stats + 1*256;
  float* s2sum = stats + 2*256;  float* s2sq = stats + 3*256;
  float* s3sum = stats + 4*256;  float* s3sq = stats + 5*256;
  size_t off = 6*256*sizeof(float);
  int* idx = (int*)(ws + off);                off += (size_t)B_*M_*K_*4;
  ushort_t* ftr_t = (ushort_t*)(ws + off);    off += (size_t)B_*N_*C_*2;
  ushort_t* W1b = (ushort_t*)(ws + off);      off += 128*160*2;
  ushort_t* W2b = (ushort_t*)(ws + off);      off += 128*128*2;
  ushort_t* W3b = (ushort_t*)(ws + off);      off += 256*128*2;
  ushort_t* Y1 = (ushort_t*)(ws + off);       off += (size_t)NTOT*128*2;
  ushort_t* Y2 = (ushort_t*)(ws + off);       off += (size_t)NTOT*128*2;
  unsigned int* Ymm = (unsigned int*)(ws + off); off += (size_t)B_*M_*256*4;

  float* new_xyz  = (float*)d_out;
  float* out_feat = (float*)d_out + (size_t)B_*M_*3;

  hipMemsetAsync(stats, 0, 6*256*sizeof(float), stream);
  prep_w_k<<<272, 256, 0, stream>>>(w1, w2, w3, W1b, W2b, W3b);
  transpose_feat_k<<<2048, 256, 0, stream>>>(feat, ftr_t);
  ball_query_k<<<1024, 256, 0, stream>>>(xyz, inds, new_xyz, idx);
  conv1_k<<<512, 256, 0, stream>>>(xyz, ftr_t, idx, new_xyz, W1b, b1, Y1, s1sum, s1sq);
  convB_k<128,false><<<512, 256, 0, stream>>>(Y1, W2b, b2, g1, be1, s1sum, s1sq, Y2, nullptr, s2sum, s2sq);
  convB_k<256,true ><<<512, 256, 0, stream>>>(Y2, W3b, b3, g2, be2, s2sum, s2sq, nullptr, Ymm, s3sum, s3sq);
  finalize_k<<<256, 256, 0, stream>>>(Ymm, g3, be3, s3sum, s3sq, out_feat);
}

// Round 9
// 221.428 us; speedup vs baseline: 1.4621x; 1.0163x over previous
//
#include <hip/hip_runtime.h>

#define B_ 4
#define N_ 16384
#define C_ 128
#define M_ 1024
#define K_ 32
#define NTOT (B_*M_*K_)   /* 131072 */
#define RAD2 0.16f
#define EPS_ 1e-5f

typedef unsigned short ushort_t;
typedef __bf16 bf16x8 __attribute__((ext_vector_type(8)));
typedef float f32x4 __attribute__((ext_vector_type(4)));

__device__ __forceinline__ float b2f(ushort_t u){
  unsigned int x = ((unsigned int)u) << 16;
  return __builtin_bit_cast(float, x);
}
__device__ __forceinline__ ushort_t f2b(float f){
  unsigned int u = __builtin_bit_cast(unsigned int, f);
  unsigned int r = (u + 0x7FFFu + ((u >> 16) & 1u)) >> 16;
  return (ushort_t)r;
}

// ---------------- ball query: 1 wave per query, no LDS, no barriers ---------
__global__ __launch_bounds__(256) void ball_query_k(
    const float* __restrict__ xyz, const int* __restrict__ indices,
    float* __restrict__ new_xyz, int* __restrict__ idx)
{
  int t = threadIdx.x;
  int wv = t >> 6, lane = t & 63;
  int g = blockIdx.x*4 + wv;
  int b = g >> 10;
  const float* pb = xyz + (size_t)b*N_*3;
  const float4* pb4 = (const float4*)pb;
  int qi = indices[g];
  float qx = pb[qi*3+0], qy = pb[qi*3+1], qz = pb[qi*3+2];
  if (lane < 3) new_xyz[g*3 + lane] = pb[qi*3 + lane];

  int cnt = 0, firstIdx = 0;
  int* op = idx + g*K_;

  float4 buf0[6], buf1[6];
  #pragma unroll
  for (int i = 0; i < 6; i++) buf0[i] = pb4[lane*6 + i];

  auto process = [&](const float4* buf, int chunk){
    const float* f = (const float*)buf;
    unsigned int local_mask = 0;
    #pragma unroll
    for (int j = 0; j < 8; j++){
      float dx = f[j*3+0]-qx, dy = f[j*3+1]-qy, dz = f[j*3+2]-qz;
      if (dx*dx + dy*dy + dz*dz < RAD2) local_mask |= (1u << j);
    }
    if (__ballot(local_mask != 0) == 0ull) return;
    int base = chunk*512;
    int lcnt = __popc(local_mask);
    int incl = lcnt;
    #pragma unroll
    for (int d = 1; d < 64; d <<= 1){
      int tt = __shfl_up(incl, d);
      if (lane >= d) incl += tt;
    }
    int excl = incl - lcnt;
    int total = __shfl(incl, 63);
    if (cnt == 0){
      int lf = local_mask ? (lane*8 + __builtin_ctz(local_mask)) : 0x7fffffff;
      #pragma unroll
      for (int d = 1; d < 64; d <<= 1) lf = min(lf, __shfl_xor(lf, d));
      firstIdx = base + lf;
    }
    int sl = cnt + excl;
    unsigned int m = local_mask;
    while (m && sl < K_){
      int j = __builtin_ctz(m); m &= m - 1u;
      op[sl++] = base + lane*8 + j;
    }
    cnt += total;
  };

  for (int chunk = 0; chunk < 32; chunk += 2){
    if (chunk + 1 < 32){
      #pragma unroll
      for (int i = 0; i < 6; i++) buf1[i] = pb4[(chunk+1)*384 + lane*6 + i];
    }
    process(buf0, chunk);
    if (cnt >= K_) break;
    if (chunk + 2 < 32){
      #pragma unroll
      for (int i = 0; i < 6; i++) buf0[i] = pb4[(chunk+2)*384 + lane*6 + i];
    }
    process(buf1, chunk + 1);
    if (cnt >= K_) break;
  }
  if (cnt < K_){
    for (int s = cnt + lane; s < K_; s += 64) op[s] = firstIdx;
  }
}

// ---------------- features (B,C,N) f32 -> (B,N,C) bf16 ----------------------
__global__ __launch_bounds__(256) void transpose_feat_k(
    const float* __restrict__ feat, ushort_t* __restrict__ ftr_t)
{
  __shared__ float T[32][133];
  int bi = blockIdx.x;
  int b = bi >> 9, ntile = bi & 511;
  int n0 = ntile * 32;
  int t = threadIdx.x;
  int nl = t & 31;
  #pragma unroll
  for (int ci = 0; ci < 16; ci++){
    int c = ci*8 + (t >> 5);
    T[nl][c] = feat[((size_t)b*C_ + c)*N_ + n0 + nl];
  }
  __syncthreads();
  #pragma unroll
  for (int ii = 0; ii < 2; ii++){
    int v = ii*256 + t;
    int n2 = v >> 4, seg = v & 15;
    union { ushort_t u[8]; uint4 q; } pk;
    #pragma unroll
    for (int j = 0; j < 8; j++) pk.u[j] = f2b(T[n2][seg*8 + j]);
    *(uint4*)(ftr_t + ((size_t)b*N_ + n0 + n2)*C_ + seg*8) = pk.q;
  }
}

// ---------------- weights f32 -> bf16 (W1 reordered: feat|xyz|0, stride 160) -
__global__ __launch_bounds__(256) void prep_w_k(
    const float* __restrict__ w1, const float* __restrict__ w2, const float* __restrict__ w3,
    ushort_t* __restrict__ W1b, ushort_t* __restrict__ W2b, ushort_t* __restrict__ W3b)
{
  const int T1 = 128*160, T2 = 128*128, T3 = 256*128;
  for (int e = blockIdx.x*256 + threadIdx.x; e < T1+T2+T3; e += gridDim.x*256){
    if (e < T1){
      int o = e / 160, c = e % 160;
      float v = 0.f;
      if (c < 128) v = w1[o*131 + 3 + c];
      else if (c < 131) v = w1[o*131 + (c - 128)];
      W1b[e] = f2b(v);
    } else if (e < T1+T2){
      int e2 = e - T1;
      W2b[e2] = f2b(w2[e2]);
    } else {
      int e3 = e - T1 - T2;
      W3b[e3] = f2b(w3[e3]);
    }
  }
}

// ---------------- conv1: column-split pairs (64 cols/block), GPB=8 ----------
// grid 1024: adjacent block pairs share groups, split output channels.
// Raises grid-cap 2->4 blocks/CU with unchanged GPB amortization (r6/r7
// lessons) and halves W/LDS per block. Staging read twice (L2/L3-resident).
__global__ __launch_bounds__(256, 2) void conv1_k(
    const float* __restrict__ xyz, const ushort_t* __restrict__ ftr_t,
    const int* __restrict__ idx, const float* __restrict__ new_xyz,
    const ushort_t* __restrict__ W1b, const float* __restrict__ b1,
    ushort_t* __restrict__ Y1, float* __restrict__ sumO, float* __restrict__ sqO)
{
  __shared__ alignas(16) ushort_t Xs[32*168];
  __shared__ alignas(16) float Ys[32*68];
  int t = threadIdx.x;
  int wv = t >> 6, lane = t & 63, quad = lane >> 4, l15 = lane & 15;
  int row = t >> 3, chunk = t & 7;
  int col0 = (blockIdx.x & 1) * 64;
  int blk = blockIdx.x >> 1;

  if (t < 128){
    int rr = t >> 2, cc = t & 3;
    *(uint4*)(Xs + rr*168 + 128 + cc*8) = make_uint4(0,0,0,0);
  }
  bf16x8 wf[5];
  #pragma unroll
  for (int kt = 0; kt < 5; kt++)
    wf[kt] = *(const bf16x8*)(W1b + (col0 + wv*16 + l15)*160 + kt*32 + quad*8);
  float bs_r = b1[col0 + wv*16 + l15];
  float s = 0.f, s2 = 0.f;

  const int GPB = 8;
  int g0 = blk * GPB;
  int b = g0 >> 10;
  int ia[GPB], ibv[GPB];
  #pragma unroll
  for (int i = 0; i < GPB; i++){
    ia[i]  = idx[(g0+i)*K_ + row];
    ibv[i] = idx[(g0+i)*K_ + (t & 31)];
  }
  for (int i = 0; i < GPB; i++){
    int g = g0 + i;
    const ushort_t* src = ftr_t + ((size_t)b*N_ + ia[i])*C_ + chunk*16;
    uint4 q0 = *(const uint4*)src;
    uint4 q1 = *(const uint4*)(src + 8);
    *(uint4*)(Xs + row*168 + chunk*16) = q0;
    *(uint4*)(Xs + row*168 + chunk*16 + 8) = q1;
    if (t < 32){
      const float* pp = xyz + ((size_t)b*N_ + ibv[i])*3;
      const float* qq = new_xyz + (size_t)g*3;
      unsigned int u0 = (unsigned int)f2b(pp[0]-qq[0]) | ((unsigned int)f2b(pp[1]-qq[1]) << 16);
      unsigned int u1 = (unsigned int)f2b(pp[2]-qq[2]);
      *(uint2*)(Xs + t*168 + 128) = make_uint2(u0, u1);
    }
    __syncthreads();
    bf16x8 af[2][5];
    #pragma unroll
    for (int mt = 0; mt < 2; mt++)
      #pragma unroll
      for (int kt = 0; kt < 5; kt++)
        af[mt][kt] = *(const bf16x8*)(Xs + (mt*16 + l15)*168 + kt*32 + quad*8);
    f32x4 acc[2] = {(f32x4){0,0,0,0}, (f32x4){0,0,0,0}};
    #pragma unroll
    for (int kt = 0; kt < 5; kt++){
      acc[0] = __builtin_amdgcn_mfma_f32_16x16x32_bf16(af[0][kt], wf[kt], acc[0], 0,0,0);
      acc[1] = __builtin_amdgcn_mfma_f32_16x16x32_bf16(af[1][kt], wf[kt], acc[1], 0,0,0);
    }
    {
      int o = wv*16 + l15;
      #pragma unroll
      for (int mt = 0; mt < 2; mt++)
        #pragma unroll
        for (int r = 0; r < 4; r++){
          float v = acc[mt][r] + bs_r;
          s += v; s2 += v*v;
          Ys[(mt*16 + quad*4 + r)*68 + o] = v;
        }
    }
    __syncthreads();
    {
      const float* yp = &Ys[row*68 + chunk*8];
      f32x4 y0 = *(const f32x4*)(yp);
      f32x4 y1 = *(const f32x4*)(yp + 4);
      union { ushort_t u[8]; uint4 q; } p0;
      #pragma unroll
      for (int j = 0; j < 4; j++){
        p0.u[j] = f2b(y0[j]); p0.u[4+j] = f2b(y1[j]);
      }
      *(uint4*)(Y1 + ((size_t)g*K_ + row)*128 + col0 + chunk*8) = p0.q;
    }
  }
  s  += __shfl_xor(s, 16);  s  += __shfl_xor(s, 32);
  s2 += __shfl_xor(s2, 16); s2 += __shfl_xor(s2, 32);
  if (quad == 0){
    int o = col0 + wv*16 + l15;
    atomicAdd(&sumO[o], s);
    atomicAdd(&sqO[o], s2);
  }
}

// ---------------- conv2/conv3: column-split pairs, BN staging, W in regs ----
// MAXMIN (conv3): Xs double-buffered -> single barrier per group.
template<int COUT, bool MAXMIN>
__global__ __launch_bounds__(256, 2) void convB_k(
    const ushort_t* __restrict__ Yin, const ushort_t* __restrict__ Wb,
    const float* __restrict__ bias, const float* __restrict__ g_bn,
    const float* __restrict__ beta_bn, const float* __restrict__ sumI,
    const float* __restrict__ sqI, ushort_t* __restrict__ Yout,
    unsigned int* __restrict__ Ymm, float* __restrict__ sumO, float* __restrict__ sqO)
{
  constexpr int HALF = COUT/2;
  constexpr int NT = HALF/64;           // col-tiles of 16 per wave
  constexpr int NXS = MAXMIN ? 2 : 1;
  __shared__ alignas(16) ushort_t Xs[NXS][32*136];
  __shared__ alignas(16) float Ys[MAXMIN ? 4 : 32*68];
  int t = threadIdx.x;
  int wv = t >> 6, lane = t & 63, quad = lane >> 4, l15 = lane & 15;
  int row = t >> 3, chunk = t & 7;
  int col0 = (blockIdx.x & 1) * HALF;
  int blk = blockIdx.x >> 1;

  float a_r[16], d_r[16];
  #pragma unroll
  for (int j = 0; j < 16; j++){
    int c = chunk*16 + j;
    float mu  = sumI[c] * (1.f/NTOT);
    float var = sqI[c]  * (1.f/NTOT) - mu*mu;
    float a = g_bn[c] * rsqrtf(var + EPS_);
    a_r[j] = a; d_r[j] = beta_bn[c] - a*mu;
  }
  bf16x8 wf[NT][4];
  #pragma unroll
  for (int nt = 0; nt < NT; nt++)
    #pragma unroll
    for (int kt = 0; kt < 4; kt++)
      wf[nt][kt] = *(const bf16x8*)(Wb + (col0 + wv*(NT*16) + nt*16 + l15)*128 + kt*32 + quad*8);
  float bs_r[NT];
  #pragma unroll
  for (int nt = 0; nt < NT; nt++) bs_r[nt] = bias[col0 + wv*(NT*16) + nt*16 + l15];
  float s[NT], s2[NT];
  #pragma unroll
  for (int nt = 0; nt < NT; nt++){ s[nt] = 0.f; s2[nt] = 0.f; }

  const int GPB = 8;
  int g0 = blk * GPB;
  uint4 r0, r1;
  {
    const ushort_t* src = Yin + ((size_t)g0*K_ + row)*128 + chunk*16;
    r0 = *(const uint4*)src; r1 = *(const uint4*)(src + 8);
  }
  for (int i = 0; i < GPB; i++){
    int g = g0 + i;
    ushort_t* X = Xs[MAXMIN ? (i & (NXS-1)) : 0];
    union { ushort_t u[8]; uint4 q; } i0, i1, o0, o1;
    i0.q = r0; i1.q = r1;
    #pragma unroll
    for (int j = 0; j < 8; j++){
      o0.u[j] = f2b(fmaxf(a_r[j]  *b2f(i0.u[j]) + d_r[j],   0.f));
      o1.u[j] = f2b(fmaxf(a_r[8+j]*b2f(i1.u[j]) + d_r[8+j], 0.f));
    }
    *(uint4*)(X + row*136 + chunk*16) = o0.q;
    *(uint4*)(X + row*136 + chunk*16 + 8) = o1.q;
    if (i + 1 < GPB){
      const ushort_t* src = Yin + ((size_t)(g+1)*K_ + row)*128 + chunk*16;
      r0 = *(const uint4*)src; r1 = *(const uint4*)(src + 8);
    }
    __syncthreads();
    bf16x8 af[2][4];
    #pragma unroll
    for (int mt = 0; mt < 2; mt++)
      #pragma unroll
      for (int kt = 0; kt < 4; kt++)
        af[mt][kt] = *(const bf16x8*)(X + (mt*16 + l15)*136 + kt*32 + quad*8);
    f32x4 acc[NT][2];
    #pragma unroll
    for (int nt = 0; nt < NT; nt++){ acc[nt][0] = (f32x4){0,0,0,0}; acc[nt][1] = (f32x4){0,0,0,0}; }
    #pragma unroll
    for (int nt = 0; nt < NT; nt++)
      #pragma unroll
      for (int kt = 0; kt < 4; kt++){
        acc[nt][0] = __builtin_amdgcn_mfma_f32_16x16x32_bf16(af[0][kt], wf[nt][kt], acc[nt][0], 0,0,0);
        acc[nt][1] = __builtin_amdgcn_mfma_f32_16x16x32_bf16(af[1][kt], wf[nt][kt], acc[nt][1], 0,0,0);
      }
    if constexpr (!MAXMIN){
      // NT == 1: wave covers cols col0 + wv*16 + l15
      {
        int o = wv*16 + l15;
        #pragma unroll
        for (int mt = 0; mt < 2; mt++)
          #pragma unroll
          for (int r = 0; r < 4; r++){
            float v = acc[0][mt][r] + bs_r[0];
            s[0] += v; s2[0] += v*v;
            Ys[(mt*16 + quad*4 + r)*68 + o] = v;
          }
      }
      __syncthreads();
      const float* yp = &Ys[row*68 + chunk*8];
      f32x4 y0 = *(const f32x4*)(yp);
      f32x4 y1 = *(const f32x4*)(yp + 4);
      union { ushort_t u[8]; uint4 q; } p0;
      #pragma unroll
      for (int j = 0; j < 4; j++){
        p0.u[j] = f2b(y0[j]); p0.u[4+j] = f2b(y1[j]);
      }
      *(uint4*)(Yout + ((size_t)g*K_ + row)*128 + col0 + chunk*8) = p0.q;
    } else {
      #pragma unroll
      for (int nt = 0; nt < NT; nt++){
        float v0 = acc[nt][0][0] + bs_r[nt];
        float mx = v0, mn = v0;
        s[nt] += v0; s2[nt] += v0*v0;
        #pragma unroll
        for (int mt = 0; mt < 2; mt++)
          #pragma unroll
          for (int r = 0; r < 4; r++){
            if (mt == 0 && r == 0) continue;
            float v = acc[nt][mt][r] + bs_r[nt];
            s[nt] += v; s2[nt] += v*v;
            mx = fmaxf(mx, v); mn = fminf(mn, v);
          }
        mx = fmaxf(mx, __shfl_xor(mx, 16)); mx = fmaxf(mx, __shfl_xor(mx, 32));
        mn = fminf(mn, __shfl_xor(mn, 16)); mn = fminf(mn, __shfl_xor(mn, 32));
        if (quad == 0){
          int o = col0 + wv*(NT*16) + nt*16 + l15;
          Ymm[(size_t)g*256 + o] = (unsigned int)f2b(mx) | ((unsigned int)f2b(mn) << 16);
        }
      }
      // no trailing barrier: next iteration writes the other Xs buffer
    }
  }
  #pragma unroll
  for (int nt = 0; nt < NT; nt++){
    s[nt]  += __shfl_xor(s[nt], 16);  s[nt]  += __shfl_xor(s[nt], 32);
    s2[nt] += __shfl_xor(s2[nt], 16); s2[nt] += __shfl_xor(s2[nt], 32);
    if (quad == 0){
      int o = col0 + wv*(NT*16) + nt*16 + l15;
      atomicAdd(&sumO[o], s[nt]);
      atomicAdd(&sqO[o], s2[nt]);
    }
  }
}

// ---------------- finalize: BN3 from max/min pairs, transposed store --------
__global__ __launch_bounds__(256) void finalize_k(
    const unsigned int* __restrict__ Ymm, const float* __restrict__ g3,
    const float* __restrict__ beta3, const float* __restrict__ sum3,
    const float* __restrict__ sq3, float* __restrict__ out)
{
  __shared__ float T[16][264];
  __shared__ float abn[256], dbn[256];
  int t = threadIdx.x;
  int b = blockIdx.x >> 6;
  int m0 = (blockIdx.x & 63) * 16;
  {
    float mu  = sum3[t] * (1.f/NTOT);
    float var = sq3[t]  * (1.f/NTOT) - mu*mu;
    float a = g3[t] * rsqrtf(var + EPS_);
    abn[t] = a; dbn[t] = beta3[t] - a*mu;
  }
  __syncthreads();
  #pragma unroll
  for (int i = 0; i < 4; i++){
    int v4 = i*256 + t;
    int m = v4 >> 6, oq = (v4 & 63) * 4;
    uint4 w = *(const uint4*)(Ymm + ((size_t)(b*M_ + m0 + m))*256 + oq);
    unsigned int wsv[4] = {w.x, w.y, w.z, w.w};
    float r[4];
    #pragma unroll
    for (int j = 0; j < 4; j++){
      int o = oq + j;
      float mx = b2f((ushort_t)(wsv[j] & 0xffffu));
      float mn = b2f((ushort_t)(wsv[j] >> 16));
      float a = abn[o];
      float val = (a >= 0.f) ? (a*mx + dbn[o]) : (a*mn + dbn[o]);
      r[j] = fmaxf(val, 0.f);
    }
    *(f32x4*)(&T[m][oq]) = *(f32x4*)r;
  }
  __syncthreads();
  #pragma unroll
  for (int p = 0; p < 4; p++){
    int o = p*64 + (t >> 2), c = t & 3;
    float4 v = make_float4(T[c*4+0][o], T[c*4+1][o], T[c*4+2][o], T[c*4+3][o]);
    *(float4*)(out + ((size_t)(b*256 + o))*M_ + m0 + c*4) = v;
  }
}

extern "C" void kernel_launch(void* const* d_in, const int* in_sizes, int n_in,
                              void* d_out, int out_size, void* d_ws, size_t ws_size,
                              hipStream_t stream)
{
  (void)in_sizes; (void)n_in; (void)out_size; (void)ws_size;
  const float* xyz  = (const float*)d_in[0];
  const float* feat = (const float*)d_in[1];
  const int*   inds = (const int*)d_in[2];
  const float* w1 = (const float*)d_in[3];
  const float* b1 = (const float*)d_in[4];
  const float* g1 = (const float*)d_in[5];
  const float* be1= (const float*)d_in[6];
  const float* w2 = (const float*)d_in[7];
  const float* b2 = (const float*)d_in[8];
  const float* g2 = (const float*)d_in[9];
  const float* be2= (const float*)d_in[10];
  const float* w3 = (const float*)d_in[11];
  const float* b3 = (const float*)d_in[12];
  const float* g3 = (const float*)d_in[13];
  const float* be3= (const float*)d_in[14];

  char* ws = (char*)d_ws;
  float* stats = (float*)ws;
  float* s1sum = stats + 0*256;  float* s1sq = stats + 1*256;
  float* s2sum = stats + 2*256;  float* s2sq = stats + 3*256;
  float* s3sum = stats + 4*256;  float* s3sq = stats + 5*256;
  size_t off = 6*256*sizeof(float);
  int* idx = (int*)(ws + off);                off += (size_t)B_*M_*K_*4;
  ushort_t* ftr_t = (ushort_t*)(ws + off);    off += (size_t)B_*N_*C_*2;
  ushort_t* W1b = (ushort_t*)(ws + off);      off += 128*160*2;
  ushort_t* W2b = (ushort_t*)(ws + off);      off += 128*128*2;
  ushort_t* W3b = (ushort_t*)(ws + off);      off += 256*128*2;
  ushort_t* Y1 = (ushort_t*)(ws + off);       off += (size_t)NTOT*128*2;
  ushort_t* Y2 = (ushort_t*)(ws + off);       off += (size_t)NTOT*128*2;
  unsigned int* Ymm = (unsigned int*)(ws + off); off += (size_t)B_*M_*256*4;

  float* new_xyz  = (float*)d_out;
  float* out_feat = (float*)d_out + (size_t)B_*M_*3;

  hipMemsetAsync(stats, 0, 6*256*sizeof(float), stream);
  prep_w_k<<<272, 256, 0, stream>>>(w1, w2, w3, W1b, W2b, W3b);
  transpose_feat_k<<<2048, 256, 0, stream>>>(feat, ftr_t);
  ball_query_k<<<1024, 256, 0, stream>>>(xyz, inds, new_xyz, idx);
  conv1_k<<<1024, 256, 0, stream>>>(xyz, ftr_t, idx, new_xyz, W1b, b1, Y1, s1sum, s1sq);
  convB_k<128,false><<<1024, 256, 0, stream>>>(Y1, W2b, b2, g1, be1, s1sum, s1sq, Y2, nullptr, s2sum, s2sq);
  convB_k<256,true ><<<1024, 256, 0, stream>>>(Y2, W3b, b3, g2, be2, s2sum, s2sq, nullptr, Ymm, s3sum, s3sq);
  finalize_k<<<256, 256, 0, stream>>>(Ymm, g3, be3, s3sum, s3sq, out_feat);
}